// Round 2
// baseline (898.619 us; speedup 1.0000x reference)
//
#include <hip/hip_runtime.h>
#include <math.h>

// CTC loss, T=1024 B=64 V=256 L=256 (S=513).
//  - Recursion in LINEAR domain on RAW logits (log-softmax denominator deferred:
//    per-(t,b) additive constant factors out of the log-domain recursion).
//  - cumlse[b] = sum_t logsumexp_v(logits[t,b,:]) computed by extra blocks of the
//    same kernel (massively parallel, hides behind the serial recursion).
//  - Recursion TRUNCATED to S_b = 2*label_len[b]+1 states: forward mass flows
//    strictly left->right, so higher states never affect the readout. This keeps
//    the renorm max over *relevant* states (padded-label states otherwise
//    dominate by ~e^300 and flush the readout state to zero -> inf loss).
//  - Renorm by block max every 8 steps; log2(scale) accumulates in log2acc.
//  - loss_b = cumlse[b] - ( ln(a[end]+a[end-1]) + ln2*log2acc )

constexpr int V = 256;
constexpr float LOG2E_F = 1.4426950408889634f;
constexpr float LN2_F   = 0.6931471805599453f;

__global__ __launch_bounds__(576) void ctc_main(
    const int*   __restrict__ labels,      // [B, L]
    const float* __restrict__ logits,      // [T, B, V]
    const int*   __restrict__ label_len,   // [B]
    const int*   __restrict__ logit_len,   // [B]
    float*       __restrict__ cumlse,      // [B] (pre-zeroed, atomicAdd)
    float*       __restrict__ lnterm,      // [B]
    int T, int B, int L)
{
    const int tid = threadIdx.x;

    if ((int)blockIdx.x < B) {
        // ================= recursion block: one batch element =================
        const int b = blockIdx.x;
        __shared__ float a_buf[2][514];   // alpha double buffer
        __shared__ float e_row[3][V];     // exp(raw logit) row, triple buffer
        __shared__ float redbuf[16];      // cross-wave max reduction

        const int Tb = logit_len[b];
        const int Lb = label_len[b];
        const int Sb = 2 * Lb + 1;        // truncated state count (see header)
        const int s  = tid;
        const bool active = (s < Sb);

        int  myidx  = 0;      // ext[s]: vocab index this state emits
        bool skipok = false;  // s-2 -> s transition allowed
        if (active && (s & 1)) {
            const int li = s >> 1;
            myidx  = labels[b * L + li];
            skipok = (s >= 3) ? (myidx != labels[b * L + li - 1]) : true;
        }

        // t = 0 init: only states 0 and 1 reachable; a = exp(raw logit)
        float cur = 0.f;
        if (active && s < 2) {
            cur = expf(logits[(size_t)(0 * B + b) * V + myidx]);
        }
        // preload e-row for t=1 into buffer 1%3
        if (tid < V && Tb >= 2) {
            e_row[1][tid] = exp2f(LOG2E_F * logits[(size_t)(1 * B + b) * V + tid]);
        }

        float log2acc = 0.f;
        int p = 0;
        for (int t = 1; t < Tb; ++t) {
            // ---- region A (writes): stage alpha; prefetch+exp next e-row ----
            if (active) a_buf[p][s] = cur;
            if (tid < V && (t + 1) < Tb) {
                e_row[(t + 1) % 3][tid] =
                    exp2f(LOG2E_F * logits[(size_t)((t + 1) * B + b) * V + tid]);
            }
            __syncthreads();
            // ---- region B (reads): recurrence update ----
            if (active) {
                const float nm1 = (s >= 1) ? a_buf[p][s - 1] : 0.f;
                const float nm2 = (s >= 2 && skipok) ? a_buf[p][s - 2] : 0.f;
                const float ev  = e_row[t % 3][myidx];
                cur = (cur + nm1 + nm2) * ev;
            }
            // ---- periodic renorm (every 8 steps) ----
            if ((t & 7) == 7 || t == Tb - 1) {
                float m = cur;
                #pragma unroll
                for (int o = 32; o >= 1; o >>= 1) m = fmaxf(m, __shfl_xor(m, o, 64));
                if ((tid & 63) == 0) redbuf[tid >> 6] = m;
                __syncthreads();
                float M = 1e-30f;
                #pragma unroll
                for (int w = 0; w < 9; ++w) M = fmaxf(M, redbuf[w]);
                cur *= (1.f / M);
                log2acc += log2f(M);
                // no extra barrier: next redbuf write is >=7 barriers away
            }
            p ^= 1;
        }

        // ---- finalize: ll' = ln(a[end] + a[end-1]) + ln2*log2acc ----
        if (active) a_buf[p][s] = cur;
        __syncthreads();
        if (tid == 0) {
            const int end = 2 * Lb;               // == Sb-1
            const int em1 = (end > 0) ? end - 1 : 0;
            float ssum = a_buf[p][end] + a_buf[p][em1];
            ssum = fmaxf(ssum, 1e-35f);           // inf-protection only
            lnterm[b] = logf(ssum) + LN2_F * log2acc;
        }
    } else {
        // ================= lse blocks: cumlse[b] += lse(logits[t,b,:]) =========
        const int lb   = blockIdx.x - B;
        const int wave = tid >> 6;
        const int lane = tid & 63;
        const int wavesPerBlock = blockDim.x >> 6;            // 9
        const int nLseBlocks    = gridDim.x - B;
        const int totalWaves    = nLseBlocks * wavesPerBlock;
        const int rows = T * B;
        for (int r = lb * wavesPerBlock + wave; r < rows; r += totalWaves) {
            const int t = r / B;
            const int bb = r - t * B;
            const float4 x = ((const float4*)(logits + (size_t)r * V))[lane];
            float m = fmaxf(fmaxf(x.x, x.y), fmaxf(x.z, x.w));
            #pragma unroll
            for (int o = 32; o >= 1; o >>= 1) m = fmaxf(m, __shfl_xor(m, o, 64));
            float ss = __expf(x.x - m) + __expf(x.y - m) +
                       __expf(x.z - m) + __expf(x.w - m);
            #pragma unroll
            for (int o = 32; o >= 1; o >>= 1) ss += __shfl_xor(ss, o, 64);
            if (lane == 0 && t < logit_len[bb]) {
                atomicAdd(&cumlse[bb], m + logf(ss));
            }
        }
    }
}

__global__ __launch_bounds__(64) void ctc_final(
    const float* __restrict__ cumlse,
    const float* __restrict__ lnterm,
    float* __restrict__ out, int B)
{
    const int b = threadIdx.x;
    float v = (b < B) ? (cumlse[b] - lnterm[b]) : 0.f;
    #pragma unroll
    for (int o = 32; o >= 1; o >>= 1) v += __shfl_xor(v, o, 64);
    if (threadIdx.x == 0) out[0] = v / (float)B;
}

extern "C" void kernel_launch(void* const* d_in, const int* in_sizes, int n_in,
                              void* d_out, int out_size, void* d_ws, size_t ws_size,
                              hipStream_t stream) {
    const int*   labels    = (const int*)d_in[0];
    const float* logits    = (const float*)d_in[1];
    const int*   label_len = (const int*)d_in[2];
    const int*   logit_len = (const int*)d_in[3];

    const int B = in_sizes[2];                 // 64
    const int L = in_sizes[0] / B;             // 256
    const int T = in_sizes[1] / (B * V);       // 1024

    float* cumlse = (float*)d_ws;              // [B]
    float* lnterm = cumlse + B;                // [B]

    // cumlse accumulated via atomics -> must be zeroed every launch
    hipMemsetAsync(cumlse, 0, B * sizeof(float), stream);

    const int nLse = 192;
    ctc_main<<<B + nLse, 576, 0, stream>>>(labels, logits, label_len, logit_len,
                                           cumlse, lnterm, T, B, L);
    ctc_final<<<1, 64, 0, stream>>>(cumlse, lnterm, (float*)d_out, B);
}